// Round 15
// baseline (201.278 us; speedup 1.0000x reference)
//
#include <hip/hip_runtime.h>
#include <hip/hip_fp16.h>

#define N_NODES 100000
#define N_EDGES 3200000
#define F_IN 128
#define HID 16

#define SHIFT 8
#define NPB 256                                 // nodes per bucket
#define NB 391                                  // ceil(N/256)
#define CHUNK 4096
#define NCHUNK ((N_EDGES + CHUNK - 1) / CHUNK)  // 782
#define MAXBE 9216                              // region cap per bucket (mean 8184, +11 sigma)
#define HALFR 4608                              // per half-sort output region
#define SMAX 9                                  // HALFR/512
#define CPAD 16
#define GCAP 768                                // LDS edge cap per range for 4 nodes (mean 64)

__device__ __forceinline__ float2 h2f(unsigned u) {
    __half2 h;
    *reinterpret_cast<unsigned*>(&h) = u;
    return __half22float2(h);
}
__device__ __forceinline__ unsigned f2h(float a, float b) {
    __half2 h = __floats2half2_rn(a, b);
    return *reinterpret_cast<unsigned*>(&h);
}
__device__ __forceinline__ int ntl(const int* p) { return __builtin_nontemporal_load(p); }
__device__ __forceinline__ unsigned ntlu(const unsigned* p) { return __builtin_nontemporal_load(p); }

// ---------------- partition into 391 fixed bucket regions, 512 threads, wave-scan ----------------
__global__ __launch_bounds__(512) void k_part(const int* __restrict__ src,
                                              const int* __restrict__ dst,
                                              int* __restrict__ cursor,
                                              unsigned* __restrict__ ebuf, int E) {
    __shared__ int lcnt[512];
    __shared__ int lcur[512];
    __shared__ int dlt[512];
    __shared__ int wsum[8], wpre[8];
    __shared__ unsigned sbuf[CHUNK];         // 16 KB
    __shared__ unsigned short sbkt[CHUNK];   // 8 KB
    int t = threadIdx.x;
    int lane = t & 63, wid = t >> 6;
    lcnt[t] = 0;
    __syncthreads();
    int e0 = blockIdx.x * CHUNK;
    int ne = min(CHUNK, E - e0);
    for (int e = t; e < ne; e += 512) atomicAdd(&lcnt[ntl(dst + e0 + e) >> SHIFT], 1);
    __syncthreads();
    int v = lcnt[t];
    int s = v;
#pragma unroll
    for (int o = 1; o < 64; o <<= 1) {
        int u = __shfl_up(s, o);
        if (lane >= o) s += u;
    }
    if (lane == 63) wsum[wid] = s;
    __syncthreads();
    if (t == 0) {
        int r = 0;
#pragma unroll
        for (int k = 0; k < 8; k++) {
            wpre[k] = r;
            r += wsum[k];
        }
    }
    __syncthreads();
    int o = s + wpre[wid] - v;  // exclusive prefix
    lcur[t] = o;
    if (t < NB && v) dlt[t] = t * MAXBE + atomicAdd(&cursor[t * CPAD], v) - o;
    __syncthreads();
    for (int e = t; e < ne; e += 512) {
        int d = ntl(dst + e0 + e);
        int b = d >> SHIFT;
        int p = atomicAdd(&lcur[b], 1);
        sbuf[p] = ((unsigned)ntl(src + e0 + e) << SHIFT) | (unsigned)(d & (NPB - 1));
        sbkt[p] = (unsigned short)b;
    }
    __syncthreads();
    for (int k = t; k < ne; k += 512) ebuf[k + dlt[sbkt[k]]] = sbuf[k];
}

// ---------------- half-bucket sort by EDGE RANGE: block (b,h) sorts its half independently ----------------
__global__ __launch_bounds__(512) void k_sort2h(const unsigned* __restrict__ ebuf,
                                                const int* __restrict__ cursor,
                                                int* __restrict__ ebuf2,
                                                int2* __restrict__ offseA,
                                                int2* __restrict__ offseB, int N) {
    __shared__ int hist[NPB];
    __shared__ int cur[NPB];
    __shared__ int wsum[4], wpre[4];
    __shared__ int sbufS[HALFR];  // 18 KB
    int t = threadIdx.x;
    int lane = t & 63, wid = t >> 6;
    int b = blockIdx.x >> 1, h = blockIdx.x & 1;
    if (t < NPB) hist[t] = 0;
    __syncthreads();
    int cnt = min(cursor[b * CPAD], MAXBE);
    int mid = cnt >> 1;
    int lo = h ? mid : 0;
    int ne = (h ? cnt : mid) - lo;
    int base_r = b * MAXBE + lo;
    unsigned eu[SMAX];
    int nq = 0;
    for (int e = t; e < ne; e += 512) eu[nq++] = ntlu(ebuf + base_r + e);
    for (int q = 0; q < nq; q++) atomicAdd(&hist[eu[q] & (NPB - 1u)], 1);
    __syncthreads();
    int base_w = blockIdx.x * HALFR;
    int v = (t < NPB) ? hist[t] : 0;
    if (t < NPB) {
        int s = v;
#pragma unroll
        for (int o = 1; o < 64; o <<= 1) {
            int u = __shfl_up(s, o);
            if (lane >= o) s += u;
        }
        if (lane == 63) wsum[wid] = s;
        hist[t] = s;  // stash wave-inclusive
    }
    __syncthreads();
    if (t == 0) {
        int r = 0;
#pragma unroll
        for (int k = 0; k < 4; k++) {
            wpre[k] = r;
            r += wsum[k];
        }
    }
    __syncthreads();
    if (t < NPB) {
        int ex = hist[t] + wpre[wid] - v;  // exclusive prefix
        cur[t] = ex;
        int i = b * NPB + t;
        if (i < N) {
            int2 oe = make_int2(base_w + ex, base_w + ex + v);
            if (h == 0) offseA[i] = oe;
            else        offseB[i] = oe;
        }
    }
    __syncthreads();
    for (int q = 0; q < nq; q++) {
        int p = atomicAdd(&cur[eu[q] & (NPB - 1u)], 1);
        sbufS[p] = (int)(eu[q] >> SHIFT);
    }
    __syncthreads();
    for (int k = t; k < ne; k += 512) ebuf2[base_w + k] = sbufS[k];  // coalesced
}

// ---------------- GEMM1: g = (x @ W1) * dinv, fp16 out; deg from offsets; 2 lanes/row ----------------
__global__ __launch_bounds__(256) void k_gemm1(const float* __restrict__ x,
                                               const float* __restrict__ W1,
                                               const int2* __restrict__ offseA,
                                               const int2* __restrict__ offseB,
                                               float* __restrict__ dinv,
                                               uint4* __restrict__ gt, int N) {
    __shared__ float w1s[F_IN * HID];  // 8 KB
    for (int idx = threadIdx.x; idx < F_IN * HID; idx += 256) w1s[idx] = W1[idx];
    __syncthreads();
    int t = threadIdx.x;
    int r = t >> 1, hf = t & 1;
    int i = blockIdx.x * 128 + r;
    float acc[HID];
#pragma unroll
    for (int n = 0; n < HID; n++) acc[n] = 0.f;
    if (i < N) {
        const float4* xr = (const float4*)(x + (size_t)i * F_IN + hf * (F_IN / 2));
#pragma unroll 4
        for (int k4 = 0; k4 < F_IN / 8; k4++) {
            float4 xv = xr[k4];
            int k = hf * (F_IN / 2) + k4 * 4;
#pragma unroll
            for (int n = 0; n < HID; n++) {
                acc[n] += xv.x * w1s[(k + 0) * HID + n] + xv.y * w1s[(k + 1) * HID + n] +
                          xv.z * w1s[(k + 2) * HID + n] + xv.w * w1s[(k + 3) * HID + n];
            }
        }
    }
#pragma unroll
    for (int n = 0; n < HID; n++) acc[n] += __shfl_xor(acc[n], 1);
    if (hf == 0 && i < N) {
        int2 oA = offseA[i], oB = offseB[i];
        int deg = (oA.y - oA.x) + (oB.y - oB.x);
        float dv = rsqrtf((float)(deg + 1));  // +1 self-loop
        dinv[i] = dv;
        uint4 w0, w1;
        w0.x = f2h(acc[0] * dv, acc[1] * dv);
        w0.y = f2h(acc[2] * dv, acc[3] * dv);
        w0.z = f2h(acc[4] * dv, acc[5] * dv);
        w0.w = f2h(acc[6] * dv, acc[7] * dv);
        w1.x = f2h(acc[8] * dv, acc[9] * dv);
        w1.y = f2h(acc[10] * dv, acc[11] * dv);
        w1.z = f2h(acc[12] * dv, acc[13] * dv);
        w1.w = f2h(acc[14] * dv, acc[15] * dv);
        gt[2 * (size_t)i] = w0;
        gt[2 * (size_t)i + 1] = w1;
    }
}

// ---------------- gather conv1 + fused (h1@W2).wf dots -> q ----------------
// Block = 4 waves = 4 nodes; edge lists LDS-staged via nt loads; wave per node,
// 8 edges x 8 slices; epilogue computes q[i] = dv*(h1.v2lo, h1.v2hi).
__global__ __launch_bounds__(256) void k_gather1(const unsigned* __restrict__ gtu,
                                                 const int2* __restrict__ offseA,
                                                 const int2* __restrict__ offseB,
                                                 const int* __restrict__ ebuf2,
                                                 const float* __restrict__ dinv,
                                                 const float* __restrict__ b1,
                                                 const float* __restrict__ W2,
                                                 const float* __restrict__ Wf,
                                                 float2* __restrict__ q, int N) {
    __shared__ int eAs[GCAP];
    __shared__ int eBs[GCAP];
    __shared__ float v2[32];  // [0:16)=W2@wf_lo, [16:32)=W2@wf_hi
    int t = threadIdx.x;
    if (t < 32) {
        int k = t & 15, hi = t >> 4;
        float s = 0.f;
#pragma unroll
        for (int n = 0; n < HID; n++) s += W2[k * HID + n] * Wf[hi * HID + n];
        v2[t] = s;
    }
    int i0 = blockIdx.x * 4;  // N % 4 == 0
    int sA = offseA[i0].x, tA = offseA[i0 + 3].y;
    int sB = offseB[i0].x, tB = offseB[i0 + 3].y;
    int lA = tA - sA, lB = tB - sB;
    for (int k = t; k < lA; k += 256) eAs[k] = ntl(ebuf2 + sA + k);
    for (int k = t; k < lB; k += 256) eBs[k] = ntl(ebuf2 + sB + k);
    __syncthreads();
    int wid = t >> 6, lane = t & 63;
    int i = i0 + wid;
    int eo = lane >> 3, s = lane & 7;
    int2 oA = offseA[i], oB = offseB[i];
    int a0 = oA.x - sA, a1 = oA.y - sA;
    int c0 = oB.x - sB, c1 = oB.y - sB;
    float2 a = make_float2(0.f, 0.f);
    for (int e = a0 + eo; e < a1; e += 8) {
        float2 f = h2f(gtu[eAs[e] * 8 + s]);
        a.x += f.x;
        a.y += f.y;
    }
    for (int e = c0 + eo; e < c1; e += 8) {
        float2 f = h2f(gtu[eBs[e] * 8 + s]);
        a.x += f.x;
        a.y += f.y;
    }
    a.x += __shfl_xor(a.x, 8);  a.y += __shfl_xor(a.y, 8);
    a.x += __shfl_xor(a.x, 16); a.y += __shfl_xor(a.y, 16);
    a.x += __shfl_xor(a.x, 32); a.y += __shfl_xor(a.y, 32);
    if (eo == 0) {
        float2 f = h2f(gtu[i * 8 + s]);  // self-loop
        a.x += f.x;
        a.y += f.y;
        float dv = dinv[i];
        float2 bb = ((const float2*)b1)[s];
        float o0 = fmaxf(dv * a.x + bb.x, 0.f);  // h1[2s]
        float o1 = fmaxf(dv * a.y + bb.y, 0.f);  // h1[2s+1]
        float qs = o0 * v2[2 * s] + o1 * v2[2 * s + 1];
        float qd = o0 * v2[16 + 2 * s] + o1 * v2[16 + 2 * s + 1];
        qs += __shfl_xor(qs, 1); qd += __shfl_xor(qd, 1);
        qs += __shfl_xor(qs, 2); qd += __shfl_xor(qd, 2);
        qs += __shfl_xor(qs, 4); qd += __shfl_xor(qd, 4);
        if (s == 0) q[i] = make_float2(dv * qs, dv * qd);
    }
}

// ---------------- gather conv2 on scalars over two ranges ----------------
__global__ __launch_bounds__(256) void k_gather2(const float2* __restrict__ q,
                                                 const int2* __restrict__ offseA,
                                                 const int2* __restrict__ offseB,
                                                 const int* __restrict__ ebuf2,
                                                 const float* __restrict__ dinv,
                                                 const float* __restrict__ b2,
                                                 const float* __restrict__ Wf,
                                                 const float* __restrict__ bf,
                                                 float2* __restrict__ nd, int N) {
    __shared__ float2 C;
    if (threadIdx.x == 0) {
        float c1 = 0.f, c2 = 0.f;
#pragma unroll
        for (int k = 0; k < HID; k++) {
            c1 += b2[k] * Wf[k];
            c2 += b2[k] * Wf[16 + k];
        }
        C = make_float2(c1, c2 + bf[0]);
    }
    __syncthreads();
    int grp = threadIdx.x >> 4, l = threadIdx.x & 15;
    int i = blockIdx.x * 16 + grp;
    if (i >= N) return;
    int2 oA = offseA[i], oB = offseB[i];
    float2 a = make_float2(0.f, 0.f);
    for (int e = oA.x + l; e < oA.y; e += 16) {
        float2 qq = q[ntl(ebuf2 + e)];
        a.x += qq.x;
        a.y += qq.y;
    }
    for (int e = oB.x + l; e < oB.y; e += 16) {
        float2 qq = q[ntl(ebuf2 + e)];
        a.x += qq.x;
        a.y += qq.y;
    }
    a.x += __shfl_xor(a.x, 1); a.y += __shfl_xor(a.y, 1);
    a.x += __shfl_xor(a.x, 2); a.y += __shfl_xor(a.y, 2);
    a.x += __shfl_xor(a.x, 4); a.y += __shfl_xor(a.y, 4);
    a.x += __shfl_xor(a.x, 8); a.y += __shfl_xor(a.y, 8);
    if (l == 0) {
        float2 self = q[i];
        float dv = dinv[i];
        nd[i] = make_float2(dv * (a.x + self.x) + C.x, dv * (a.y + self.y) + C.y);
    }
}

// ---------------- edge scoring: 8 B random reads from L2-resident nd ----------------
__global__ __launch_bounds__(256) void k_edge2(const int* __restrict__ src,
                                               const int* __restrict__ dst,
                                               const float2* __restrict__ nd,
                                               float* __restrict__ pred, int E) {
    int e = blockIdx.x * 256 + threadIdx.x;
    if (e >= E) return;
    float v = nd[ntl(src + e)].x + nd[ntl(dst + e)].y;
    __builtin_nontemporal_store(v, pred + e);
}

extern "C" void kernel_launch(void* const* d_in, const int* in_sizes, int n_in,
                              void* d_out, int out_size, void* d_ws, size_t ws_size,
                              hipStream_t stream) {
    const float* x  = (const float*)d_in[0];
    const int*   ei = (const int*)d_in[1];
    const float* W1 = (const float*)d_in[2];
    const float* b1 = (const float*)d_in[3];
    const float* W2 = (const float*)d_in[4];
    const float* b2 = (const float*)d_in[5];
    const float* Wf = (const float*)d_in[6];
    const float* bf = (const float*)d_in[7];
    float* pred = (float*)d_out;

    const int N = N_NODES, E = N_EDGES;
    const int* src = ei;
    const int* dst = ei + E;

    // workspace (bytes); gt and q alias ebuf (dead after k_sort2h). Total ~33 MB.
    char* w = (char*)d_ws;
    int*      cursor = (int*)(w + 0x0);           // 25 KB (stride CPAD)
    float*    dinv   = (float*)(w + 0x10000);     // 400 KB
    int2*     offseA = (int2*)(w + 0x80000);      // 800 KB
    int2*     offseB = (int2*)(w + 0x150000);     // 800 KB
    float2*   nd     = (float2*)(w + 0x220000);   // 800 KB
    unsigned* ebuf   = (unsigned*)(w + 0x3C0000); // 391*9216*4 = 14.42 MB (dead after sort2h)
    uint4*    gt     = (uint4*)(w + 0x3C0000);    // 3.2 MB (aliases ebuf; live gemm1->gather1)
    float2*   q      = (float2*)(w + 0x700000);   // 800 KB (aliases ebuf; live gather1->edge2)
    int*      ebuf2  = (int*)(w + 0x11A0000);     // 782*4608*4 = 14.42 MB -> end ~0x1FB0000

    const int B = 256;
    int gE   = (E + B - 1) / B;     // 12500
    int gN2  = (N + 127) / 128;     // 782 (gemm1, 2 lanes/row)
    int gN4  = N / 4;               // 25000 (4 nodes per 256-thr block)
    int gN16 = (N + 15) / 16;       // 6250 (16 lanes per node)

    hipMemsetAsync(cursor, 0, NB * CPAD * sizeof(int), stream);
    k_part<<<NCHUNK, 512, 0, stream>>>(src, dst, cursor, ebuf, E);
    k_sort2h<<<2 * NB, 512, 0, stream>>>(ebuf, cursor, ebuf2, offseA, offseB, N);
    k_gemm1<<<gN2, B, 0, stream>>>(x, W1, offseA, offseB, dinv, gt, N);
    k_gather1<<<gN4, B, 0, stream>>>((const unsigned*)gt, offseA, offseB, ebuf2, dinv, b1,
                                     W2, Wf, q, N);
    k_gather2<<<gN16, B, 0, stream>>>(q, offseA, offseB, ebuf2, dinv, b2, Wf, bf, nd, N);
    k_edge2<<<gE, B, 0, stream>>>(src, dst, nd, pred, E);
}

// Round 16
// 183.874 us; speedup vs baseline: 1.0947x; 1.0947x over previous
//
#include <hip/hip_runtime.h>
#include <hip/hip_fp16.h>

#define N_NODES 100000
#define N_EDGES 3200000
#define F_IN 128
#define HID 16

#define SHIFT 8
#define NPB 256                                 // nodes per bucket
#define NB 391                                  // ceil(N/256)
#define CHUNK 4096
#define NCHUNK ((N_EDGES + CHUNK - 1) / CHUNK)  // 782
#define MAXBE 9216                              // region cap per bucket (mean 8184, +11 sigma)
#define HALFR 4608                              // per half-sort output region
#define SMAX 9                                  // HALFR/512
#define CPAD 16

__device__ __forceinline__ float2 h2f(unsigned u) {
    __half2 h;
    *reinterpret_cast<unsigned*>(&h) = u;
    return __half22float2(h);
}
__device__ __forceinline__ unsigned f2h(float a, float b) {
    __half2 h = __floats2half2_rn(a, b);
    return *reinterpret_cast<unsigned*>(&h);
}

// ---------------- partition into 391 fixed bucket regions, 512 threads, wave-scan ----------------
__global__ __launch_bounds__(512) void k_part(const int* __restrict__ src,
                                              const int* __restrict__ dst,
                                              int* __restrict__ cursor,
                                              unsigned* __restrict__ ebuf, int E) {
    __shared__ int lcnt[512];
    __shared__ int lcur[512];
    __shared__ int dlt[512];
    __shared__ int wsum[8], wpre[8];
    __shared__ unsigned sbuf[CHUNK];         // 16 KB
    __shared__ unsigned short sbkt[CHUNK];   // 8 KB
    int t = threadIdx.x;
    int lane = t & 63, wid = t >> 6;
    lcnt[t] = 0;
    __syncthreads();
    int e0 = blockIdx.x * CHUNK;
    int ne = min(CHUNK, E - e0);
    for (int e = t; e < ne; e += 512) atomicAdd(&lcnt[dst[e0 + e] >> SHIFT], 1);
    __syncthreads();
    int v = lcnt[t];
    int s = v;
#pragma unroll
    for (int o = 1; o < 64; o <<= 1) {
        int u = __shfl_up(s, o);
        if (lane >= o) s += u;
    }
    if (lane == 63) wsum[wid] = s;
    __syncthreads();
    if (t == 0) {
        int r = 0;
#pragma unroll
        for (int k = 0; k < 8; k++) {
            wpre[k] = r;
            r += wsum[k];
        }
    }
    __syncthreads();
    int o = s + wpre[wid] - v;  // exclusive prefix
    lcur[t] = o;
    if (t < NB && v) dlt[t] = t * MAXBE + atomicAdd(&cursor[t * CPAD], v) - o;
    __syncthreads();
    for (int e = t; e < ne; e += 512) {
        int d = dst[e0 + e];
        int b = d >> SHIFT;
        int p = atomicAdd(&lcur[b], 1);
        sbuf[p] = ((unsigned)src[e0 + e] << SHIFT) | (unsigned)(d & (NPB - 1));
        sbkt[p] = (unsigned short)b;
    }
    __syncthreads();
    for (int k = t; k < ne; k += 512) ebuf[k + dlt[sbkt[k]]] = sbuf[k];
}

// ---------------- half-bucket sort by EDGE RANGE: block (b,h) sorts its half independently ----------------
__global__ __launch_bounds__(512) void k_sort2h(const unsigned* __restrict__ ebuf,
                                                const int* __restrict__ cursor,
                                                int* __restrict__ ebuf2,
                                                int2* __restrict__ offseA,
                                                int2* __restrict__ offseB, int N) {
    __shared__ int hist[NPB];
    __shared__ int cur[NPB];
    __shared__ int wsum[4], wpre[4];
    __shared__ int sbufS[HALFR];  // 18 KB
    int t = threadIdx.x;
    int lane = t & 63, wid = t >> 6;
    int b = blockIdx.x >> 1, h = blockIdx.x & 1;
    if (t < NPB) hist[t] = 0;
    __syncthreads();
    int cnt = min(cursor[b * CPAD], MAXBE);
    int mid = cnt >> 1;
    int lo = h ? mid : 0;
    int ne = (h ? cnt : mid) - lo;
    int base_r = b * MAXBE + lo;
    unsigned eu[SMAX];
    int nq = 0;
    for (int e = t; e < ne; e += 512) eu[nq++] = ebuf[base_r + e];
    for (int q = 0; q < nq; q++) atomicAdd(&hist[eu[q] & (NPB - 1u)], 1);
    __syncthreads();
    int base_w = blockIdx.x * HALFR;
    int v = (t < NPB) ? hist[t] : 0;
    if (t < NPB) {
        int s = v;
#pragma unroll
        for (int o = 1; o < 64; o <<= 1) {
            int u = __shfl_up(s, o);
            if (lane >= o) s += u;
        }
        if (lane == 63) wsum[wid] = s;
        hist[t] = s;  // stash wave-inclusive
    }
    __syncthreads();
    if (t == 0) {
        int r = 0;
#pragma unroll
        for (int k = 0; k < 4; k++) {
            wpre[k] = r;
            r += wsum[k];
        }
    }
    __syncthreads();
    if (t < NPB) {
        int ex = hist[t] + wpre[wid] - v;  // exclusive prefix
        cur[t] = ex;
        int i = b * NPB + t;
        if (i < N) {
            int2 oe = make_int2(base_w + ex, base_w + ex + v);
            if (h == 0) offseA[i] = oe;
            else        offseB[i] = oe;
        }
    }
    __syncthreads();
    for (int q = 0; q < nq; q++) {
        int p = atomicAdd(&cur[eu[q] & (NPB - 1u)], 1);
        sbufS[p] = (int)(eu[q] >> SHIFT);
    }
    __syncthreads();
    for (int k = t; k < ne; k += 512) ebuf2[base_w + k] = sbufS[k];  // coalesced
}

// ---------------- GEMM1: g = (x @ W1) * dinv, fp16 out; deg from offsets; 2 lanes/row ----------------
__global__ __launch_bounds__(256) void k_gemm1(const float* __restrict__ x,
                                               const float* __restrict__ W1,
                                               const int2* __restrict__ offseA,
                                               const int2* __restrict__ offseB,
                                               float* __restrict__ dinv,
                                               uint4* __restrict__ gt, int N) {
    __shared__ float w1s[F_IN * HID];  // 8 KB
    for (int idx = threadIdx.x; idx < F_IN * HID; idx += 256) w1s[idx] = W1[idx];
    __syncthreads();
    int t = threadIdx.x;
    int r = t >> 1, hf = t & 1;
    int i = blockIdx.x * 128 + r;
    float acc[HID];
#pragma unroll
    for (int n = 0; n < HID; n++) acc[n] = 0.f;
    if (i < N) {
        const float4* xr = (const float4*)(x + (size_t)i * F_IN + hf * (F_IN / 2));
#pragma unroll 4
        for (int k4 = 0; k4 < F_IN / 8; k4++) {
            float4 xv = xr[k4];
            int k = hf * (F_IN / 2) + k4 * 4;
#pragma unroll
            for (int n = 0; n < HID; n++) {
                acc[n] += xv.x * w1s[(k + 0) * HID + n] + xv.y * w1s[(k + 1) * HID + n] +
                          xv.z * w1s[(k + 2) * HID + n] + xv.w * w1s[(k + 3) * HID + n];
            }
        }
    }
#pragma unroll
    for (int n = 0; n < HID; n++) acc[n] += __shfl_xor(acc[n], 1);
    if (hf == 0 && i < N) {
        int2 oA = offseA[i], oB = offseB[i];
        int deg = (oA.y - oA.x) + (oB.y - oB.x);
        float dv = rsqrtf((float)(deg + 1));  // +1 self-loop
        dinv[i] = dv;
        uint4 w0, w1;
        w0.x = f2h(acc[0] * dv, acc[1] * dv);
        w0.y = f2h(acc[2] * dv, acc[3] * dv);
        w0.z = f2h(acc[4] * dv, acc[5] * dv);
        w0.w = f2h(acc[6] * dv, acc[7] * dv);
        w1.x = f2h(acc[8] * dv, acc[9] * dv);
        w1.y = f2h(acc[10] * dv, acc[11] * dv);
        w1.z = f2h(acc[12] * dv, acc[13] * dv);
        w1.w = f2h(acc[14] * dv, acc[15] * dv);
        gt[2 * (size_t)i] = w0;
        gt[2 * (size_t)i + 1] = w1;
    }
}

// ---------------- gather conv1 + fused (h1@W2).wf dots -> q (direct loads, no staging) ----------------
// Wave per node; 8 edges x 8 slices; epilogue computes q[i] = dv*(h1.v2lo, h1.v2hi).
__global__ __launch_bounds__(256) void k_gather1(const unsigned* __restrict__ gtu,
                                                 const int2* __restrict__ offseA,
                                                 const int2* __restrict__ offseB,
                                                 const int* __restrict__ ebuf2,
                                                 const float* __restrict__ dinv,
                                                 const float* __restrict__ b1,
                                                 const float* __restrict__ W2,
                                                 const float* __restrict__ Wf,
                                                 float2* __restrict__ q, int N) {
    __shared__ float v2[32];  // [0:16)=W2@wf_lo, [16:32)=W2@wf_hi
    int t = threadIdx.x;
    if (t < 32) {
        int k = t & 15, hi = t >> 4;
        float s = 0.f;
#pragma unroll
        for (int n = 0; n < HID; n++) s += W2[k * HID + n] * Wf[hi * HID + n];
        v2[t] = s;
    }
    __syncthreads();
    int i = (blockIdx.x * 256 + t) >> 6;  // node = global wave id
    int lane = t & 63;
    if (i >= N) return;
    int eo = lane >> 3, s = lane & 7;
    int2 oA = offseA[i], oB = offseB[i];
    float2 a = make_float2(0.f, 0.f);
    for (int e = oA.x + eo; e < oA.y; e += 8) {
        float2 f = h2f(gtu[ebuf2[e] * 8 + s]);
        a.x += f.x;
        a.y += f.y;
    }
    for (int e = oB.x + eo; e < oB.y; e += 8) {
        float2 f = h2f(gtu[ebuf2[e] * 8 + s]);
        a.x += f.x;
        a.y += f.y;
    }
    a.x += __shfl_xor(a.x, 8);  a.y += __shfl_xor(a.y, 8);
    a.x += __shfl_xor(a.x, 16); a.y += __shfl_xor(a.y, 16);
    a.x += __shfl_xor(a.x, 32); a.y += __shfl_xor(a.y, 32);
    if (eo == 0) {
        float2 f = h2f(gtu[i * 8 + s]);  // self-loop
        a.x += f.x;
        a.y += f.y;
        float dv = dinv[i];
        float2 bb = ((const float2*)b1)[s];
        float o0 = fmaxf(dv * a.x + bb.x, 0.f);  // h1[2s]
        float o1 = fmaxf(dv * a.y + bb.y, 0.f);  // h1[2s+1]
        float qs = o0 * v2[2 * s] + o1 * v2[2 * s + 1];
        float qd = o0 * v2[16 + 2 * s] + o1 * v2[16 + 2 * s + 1];
        qs += __shfl_xor(qs, 1); qd += __shfl_xor(qd, 1);
        qs += __shfl_xor(qs, 2); qd += __shfl_xor(qd, 2);
        qs += __shfl_xor(qs, 4); qd += __shfl_xor(qd, 4);
        if (s == 0) q[i] = make_float2(dv * qs, dv * qd);
    }
}

// ---------------- gather conv2 on scalars over two ranges ----------------
__global__ __launch_bounds__(256) void k_gather2(const float2* __restrict__ q,
                                                 const int2* __restrict__ offseA,
                                                 const int2* __restrict__ offseB,
                                                 const int* __restrict__ ebuf2,
                                                 const float* __restrict__ dinv,
                                                 const float* __restrict__ b2,
                                                 const float* __restrict__ Wf,
                                                 const float* __restrict__ bf,
                                                 float2* __restrict__ nd, int N) {
    __shared__ float2 C;
    if (threadIdx.x == 0) {
        float c1 = 0.f, c2 = 0.f;
#pragma unroll
        for (int k = 0; k < HID; k++) {
            c1 += b2[k] * Wf[k];
            c2 += b2[k] * Wf[16 + k];
        }
        C = make_float2(c1, c2 + bf[0]);
    }
    __syncthreads();
    int grp = threadIdx.x >> 4, l = threadIdx.x & 15;
    int i = blockIdx.x * 16 + grp;
    if (i >= N) return;
    int2 oA = offseA[i], oB = offseB[i];
    float2 a = make_float2(0.f, 0.f);
    for (int e = oA.x + l; e < oA.y; e += 16) {
        float2 qq = q[ebuf2[e]];
        a.x += qq.x;
        a.y += qq.y;
    }
    for (int e = oB.x + l; e < oB.y; e += 16) {
        float2 qq = q[ebuf2[e]];
        a.x += qq.x;
        a.y += qq.y;
    }
    a.x += __shfl_xor(a.x, 1); a.y += __shfl_xor(a.y, 1);
    a.x += __shfl_xor(a.x, 2); a.y += __shfl_xor(a.y, 2);
    a.x += __shfl_xor(a.x, 4); a.y += __shfl_xor(a.y, 4);
    a.x += __shfl_xor(a.x, 8); a.y += __shfl_xor(a.y, 8);
    if (l == 0) {
        float2 self = q[i];
        float dv = dinv[i];
        nd[i] = make_float2(dv * (a.x + self.x) + C.x, dv * (a.y + self.y) + C.y);
    }
}

// ---------------- edge scoring: 8 B random reads from L2-resident nd ----------------
__global__ __launch_bounds__(256) void k_edge2(const int* __restrict__ src,
                                               const int* __restrict__ dst,
                                               const float2* __restrict__ nd,
                                               float* __restrict__ pred, int E) {
    int e = blockIdx.x * 256 + threadIdx.x;
    if (e >= E) return;
    pred[e] = nd[src[e]].x + nd[dst[e]].y;
}

extern "C" void kernel_launch(void* const* d_in, const int* in_sizes, int n_in,
                              void* d_out, int out_size, void* d_ws, size_t ws_size,
                              hipStream_t stream) {
    const float* x  = (const float*)d_in[0];
    const int*   ei = (const int*)d_in[1];
    const float* W1 = (const float*)d_in[2];
    const float* b1 = (const float*)d_in[3];
    const float* W2 = (const float*)d_in[4];
    const float* b2 = (const float*)d_in[5];
    const float* Wf = (const float*)d_in[6];
    const float* bf = (const float*)d_in[7];
    float* pred = (float*)d_out;

    const int N = N_NODES, E = N_EDGES;
    const int* src = ei;
    const int* dst = ei + E;

    // workspace (bytes); gt and q alias ebuf (dead after k_sort2h). Total ~33 MB.
    char* w = (char*)d_ws;
    int*      cursor = (int*)(w + 0x0);           // 25 KB (stride CPAD)
    float*    dinv   = (float*)(w + 0x10000);     // 400 KB
    int2*     offseA = (int2*)(w + 0x80000);      // 800 KB
    int2*     offseB = (int2*)(w + 0x150000);     // 800 KB
    float2*   nd     = (float2*)(w + 0x220000);   // 800 KB
    unsigned* ebuf   = (unsigned*)(w + 0x3C0000); // 391*9216*4 = 14.42 MB (dead after sort2h)
    uint4*    gt     = (uint4*)(w + 0x3C0000);    // 3.2 MB (aliases ebuf; live gemm1->gather1)
    float2*   q      = (float2*)(w + 0x700000);   // 800 KB (aliases ebuf; live gather1->edge2)
    int*      ebuf2  = (int*)(w + 0x11A0000);     // 782*4608*4 = 14.42 MB -> end ~0x1FB0000

    const int B = 256;
    int gE   = (E + B - 1) / B;     // 12500
    int gN2  = (N + 127) / 128;     // 782 (gemm1, 2 lanes/row)
    int gN64 = (N * 64) / B;        // 25000 (wave per node)
    int gN16 = (N + 15) / 16;       // 6250 (16 lanes per node)

    hipMemsetAsync(cursor, 0, NB * CPAD * sizeof(int), stream);
    k_part<<<NCHUNK, 512, 0, stream>>>(src, dst, cursor, ebuf, E);
    k_sort2h<<<2 * NB, 512, 0, stream>>>(ebuf, cursor, ebuf2, offseA, offseB, N);
    k_gemm1<<<gN2, B, 0, stream>>>(x, W1, offseA, offseB, dinv, gt, N);
    k_gather1<<<gN64, B, 0, stream>>>((const unsigned*)gt, offseA, offseB, ebuf2, dinv, b1,
                                      W2, Wf, q, N);
    k_gather2<<<gN16, B, 0, stream>>>(q, offseA, offseB, ebuf2, dinv, b2, Wf, bf, nd, N);
    k_edge2<<<gE, B, 0, stream>>>(src, dst, nd, pred, E);
}

// Round 17
// 179.944 us; speedup vs baseline: 1.1186x; 1.0218x over previous
//
#include <hip/hip_runtime.h>
#include <hip/hip_fp16.h>

#define N_NODES 100000
#define N_EDGES 3200000
#define F_IN 128
#define HID 16

#define SHIFT 8
#define NPB 256                                 // nodes per bucket
#define NB 391                                  // ceil(N/256)
#define CHUNK 4096
#define NCHUNK ((N_EDGES + CHUNK - 1) / CHUNK)  // 782
#define MAXBE 9216                              // region cap per bucket (mean 8184, +11 sigma)
#define HALFR 4608                              // per half-sort output region
#define SMAX 9                                  // HALFR/512
#define CPAD 16

__device__ __forceinline__ float2 h2f(unsigned u) {
    __half2 h;
    *reinterpret_cast<unsigned*>(&h) = u;
    return __half22float2(h);
}
__device__ __forceinline__ unsigned f2h(float a, float b) {
    __half2 h = __floats2half2_rn(a, b);
    return *reinterpret_cast<unsigned*>(&h);
}

// ---------------- partition into 391 fixed bucket regions, 512 threads, wave-scan ----------------
__global__ __launch_bounds__(512) void k_part(const int* __restrict__ src,
                                              const int* __restrict__ dst,
                                              int* __restrict__ cursor,
                                              unsigned* __restrict__ ebuf, int E) {
    __shared__ int lcnt[512];
    __shared__ int lcur[512];
    __shared__ int dlt[512];
    __shared__ int wsum[8], wpre[8];
    __shared__ unsigned sbuf[CHUNK];         // 16 KB
    __shared__ unsigned short sbkt[CHUNK];   // 8 KB
    int t = threadIdx.x;
    int lane = t & 63, wid = t >> 6;
    lcnt[t] = 0;
    __syncthreads();
    int e0 = blockIdx.x * CHUNK;
    int ne = min(CHUNK, E - e0);
    for (int e = t; e < ne; e += 512) atomicAdd(&lcnt[dst[e0 + e] >> SHIFT], 1);
    __syncthreads();
    int v = lcnt[t];
    int s = v;
#pragma unroll
    for (int o = 1; o < 64; o <<= 1) {
        int u = __shfl_up(s, o);
        if (lane >= o) s += u;
    }
    if (lane == 63) wsum[wid] = s;
    __syncthreads();
    if (t == 0) {
        int r = 0;
#pragma unroll
        for (int k = 0; k < 8; k++) {
            wpre[k] = r;
            r += wsum[k];
        }
    }
    __syncthreads();
    int o = s + wpre[wid] - v;  // exclusive prefix
    lcur[t] = o;
    if (t < NB && v) dlt[t] = t * MAXBE + atomicAdd(&cursor[t * CPAD], v) - o;
    __syncthreads();
    for (int e = t; e < ne; e += 512) {
        int d = dst[e0 + e];
        int b = d >> SHIFT;
        int p = atomicAdd(&lcur[b], 1);
        sbuf[p] = ((unsigned)src[e0 + e] << SHIFT) | (unsigned)(d & (NPB - 1));
        sbkt[p] = (unsigned short)b;
    }
    __syncthreads();
    for (int k = t; k < ne; k += 512) ebuf[k + dlt[sbkt[k]]] = sbuf[k];
}

// ---------------- half-bucket sort by EDGE RANGE: block (b,h) sorts its half independently ----------------
__global__ __launch_bounds__(512) void k_sort2h(const unsigned* __restrict__ ebuf,
                                                const int* __restrict__ cursor,
                                                int* __restrict__ ebuf2,
                                                int2* __restrict__ offseA,
                                                int2* __restrict__ offseB, int N) {
    __shared__ int hist[NPB];
    __shared__ int cur[NPB];
    __shared__ int wsum[4], wpre[4];
    __shared__ int sbufS[HALFR];  // 18 KB
    int t = threadIdx.x;
    int lane = t & 63, wid = t >> 6;
    int b = blockIdx.x >> 1, h = blockIdx.x & 1;
    if (t < NPB) hist[t] = 0;
    __syncthreads();
    int cnt = min(cursor[b * CPAD], MAXBE);
    int mid = cnt >> 1;
    int lo = h ? mid : 0;
    int ne = (h ? cnt : mid) - lo;
    int base_r = b * MAXBE + lo;
    unsigned eu[SMAX];
    int nq = 0;
    for (int e = t; e < ne; e += 512) eu[nq++] = ebuf[base_r + e];
    for (int q = 0; q < nq; q++) atomicAdd(&hist[eu[q] & (NPB - 1u)], 1);
    __syncthreads();
    int base_w = blockIdx.x * HALFR;
    int v = (t < NPB) ? hist[t] : 0;
    if (t < NPB) {
        int s = v;
#pragma unroll
        for (int o = 1; o < 64; o <<= 1) {
            int u = __shfl_up(s, o);
            if (lane >= o) s += u;
        }
        if (lane == 63) wsum[wid] = s;
        hist[t] = s;  // stash wave-inclusive
    }
    __syncthreads();
    if (t == 0) {
        int r = 0;
#pragma unroll
        for (int k = 0; k < 4; k++) {
            wpre[k] = r;
            r += wsum[k];
        }
    }
    __syncthreads();
    if (t < NPB) {
        int ex = hist[t] + wpre[wid] - v;  // exclusive prefix
        cur[t] = ex;
        int i = b * NPB + t;
        if (i < N) {
            int2 oe = make_int2(base_w + ex, base_w + ex + v);
            if (h == 0) offseA[i] = oe;
            else        offseB[i] = oe;
        }
    }
    __syncthreads();
    for (int q = 0; q < nq; q++) {
        int p = atomicAdd(&cur[eu[q] & (NPB - 1u)], 1);
        sbufS[p] = (int)(eu[q] >> SHIFT);
    }
    __syncthreads();
    for (int k = t; k < ne; k += 512) ebuf2[base_w + k] = sbufS[k];  // coalesced
}

// ---------------- GEMM1: g = (x @ W1) * dinv, fp16 out; also v2g = W2@[wf_lo|wf_hi] (block 0) ----------------
__global__ __launch_bounds__(256) void k_gemm1(const float* __restrict__ x,
                                               const float* __restrict__ W1,
                                               const float* __restrict__ W2,
                                               const float* __restrict__ Wf,
                                               const int2* __restrict__ offseA,
                                               const int2* __restrict__ offseB,
                                               float* __restrict__ dinv,
                                               uint4* __restrict__ gt,
                                               float* __restrict__ v2g, int N) {
    __shared__ float w1s[F_IN * HID];  // 8 KB
    for (int idx = threadIdx.x; idx < F_IN * HID; idx += 256) w1s[idx] = W1[idx];
    if (blockIdx.x == 0 && threadIdx.x < 32) {
        int k = threadIdx.x & 15, hi = threadIdx.x >> 4;
        float s = 0.f;
#pragma unroll
        for (int n = 0; n < HID; n++) s += W2[k * HID + n] * Wf[hi * HID + n];
        v2g[threadIdx.x] = s;
    }
    __syncthreads();
    int t = threadIdx.x;
    int r = t >> 1, hf = t & 1;
    int i = blockIdx.x * 128 + r;
    float acc[HID];
#pragma unroll
    for (int n = 0; n < HID; n++) acc[n] = 0.f;
    if (i < N) {
        const float4* xr = (const float4*)(x + (size_t)i * F_IN + hf * (F_IN / 2));
#pragma unroll 4
        for (int k4 = 0; k4 < F_IN / 8; k4++) {
            float4 xv = xr[k4];
            int k = hf * (F_IN / 2) + k4 * 4;
#pragma unroll
            for (int n = 0; n < HID; n++) {
                acc[n] += xv.x * w1s[(k + 0) * HID + n] + xv.y * w1s[(k + 1) * HID + n] +
                          xv.z * w1s[(k + 2) * HID + n] + xv.w * w1s[(k + 3) * HID + n];
            }
        }
    }
#pragma unroll
    for (int n = 0; n < HID; n++) acc[n] += __shfl_xor(acc[n], 1);
    if (hf == 0 && i < N) {
        int2 oA = offseA[i], oB = offseB[i];
        int deg = (oA.y - oA.x) + (oB.y - oB.x);
        float dv = rsqrtf((float)(deg + 1));  // +1 self-loop
        dinv[i] = dv;
        uint4 w0, w1;
        w0.x = f2h(acc[0] * dv, acc[1] * dv);
        w0.y = f2h(acc[2] * dv, acc[3] * dv);
        w0.z = f2h(acc[4] * dv, acc[5] * dv);
        w0.w = f2h(acc[6] * dv, acc[7] * dv);
        w1.x = f2h(acc[8] * dv, acc[9] * dv);
        w1.y = f2h(acc[10] * dv, acc[11] * dv);
        w1.z = f2h(acc[12] * dv, acc[13] * dv);
        w1.w = f2h(acc[14] * dv, acc[15] * dv);
        gt[2 * (size_t)i] = w0;
        gt[2 * (size_t)i + 1] = w1;
    }
}

// ---------------- gather conv1 + fused dots via precomputed v2g (lean body, no LDS) ----------------
// Wave per node; 8 edges x 8 slices; epilogue q[i] = dv*(h1.v2lo, h1.v2hi).
__global__ __launch_bounds__(256) void k_gather1(const unsigned* __restrict__ gtu,
                                                 const int2* __restrict__ offseA,
                                                 const int2* __restrict__ offseB,
                                                 const int* __restrict__ ebuf2,
                                                 const float* __restrict__ dinv,
                                                 const float* __restrict__ b1,
                                                 const float* __restrict__ v2g,
                                                 float2* __restrict__ q, int N) {
    int i = (blockIdx.x * 256 + threadIdx.x) >> 6;  // node = global wave id
    int lane = threadIdx.x & 63;
    if (i >= N) return;
    int eo = lane >> 3, s = lane & 7;
    int2 oA = offseA[i], oB = offseB[i];
    float2 a = make_float2(0.f, 0.f);
    for (int e = oA.x + eo; e < oA.y; e += 8) {
        float2 f = h2f(gtu[ebuf2[e] * 8 + s]);
        a.x += f.x;
        a.y += f.y;
    }
    for (int e = oB.x + eo; e < oB.y; e += 8) {
        float2 f = h2f(gtu[ebuf2[e] * 8 + s]);
        a.x += f.x;
        a.y += f.y;
    }
    a.x += __shfl_xor(a.x, 8);  a.y += __shfl_xor(a.y, 8);
    a.x += __shfl_xor(a.x, 16); a.y += __shfl_xor(a.y, 16);
    a.x += __shfl_xor(a.x, 32); a.y += __shfl_xor(a.y, 32);
    if (eo == 0) {
        float2 f = h2f(gtu[i * 8 + s]);  // self-loop
        a.x += f.x;
        a.y += f.y;
        float dv = dinv[i];
        float2 bb = ((const float2*)b1)[s];
        float o0 = fmaxf(dv * a.x + bb.x, 0.f);  // h1[2s]
        float o1 = fmaxf(dv * a.y + bb.y, 0.f);  // h1[2s+1]
        float2 vlo = ((const float2*)v2g)[s];
        float2 vhi = ((const float2*)v2g)[8 + s];
        float qs = o0 * vlo.x + o1 * vlo.y;
        float qd = o0 * vhi.x + o1 * vhi.y;
        qs += __shfl_xor(qs, 1); qd += __shfl_xor(qd, 1);
        qs += __shfl_xor(qs, 2); qd += __shfl_xor(qd, 2);
        qs += __shfl_xor(qs, 4); qd += __shfl_xor(qd, 4);
        if (s == 0) q[i] = make_float2(dv * qs, dv * qd);
    }
}

// ---------------- gather conv2 on scalars over two ranges ----------------
__global__ __launch_bounds__(256) void k_gather2(const float2* __restrict__ q,
                                                 const int2* __restrict__ offseA,
                                                 const int2* __restrict__ offseB,
                                                 const int* __restrict__ ebuf2,
                                                 const float* __restrict__ dinv,
                                                 const float* __restrict__ b2,
                                                 const float* __restrict__ Wf,
                                                 const float* __restrict__ bf,
                                                 float2* __restrict__ nd, int N) {
    __shared__ float2 C;
    if (threadIdx.x == 0) {
        float c1 = 0.f, c2 = 0.f;
#pragma unroll
        for (int k = 0; k < HID; k++) {
            c1 += b2[k] * Wf[k];
            c2 += b2[k] * Wf[16 + k];
        }
        C = make_float2(c1, c2 + bf[0]);
    }
    __syncthreads();
    int grp = threadIdx.x >> 4, l = threadIdx.x & 15;
    int i = blockIdx.x * 16 + grp;
    if (i >= N) return;
    int2 oA = offseA[i], oB = offseB[i];
    float2 a = make_float2(0.f, 0.f);
    for (int e = oA.x + l; e < oA.y; e += 16) {
        float2 qq = q[ebuf2[e]];
        a.x += qq.x;
        a.y += qq.y;
    }
    for (int e = oB.x + l; e < oB.y; e += 16) {
        float2 qq = q[ebuf2[e]];
        a.x += qq.x;
        a.y += qq.y;
    }
    a.x += __shfl_xor(a.x, 1); a.y += __shfl_xor(a.y, 1);
    a.x += __shfl_xor(a.x, 2); a.y += __shfl_xor(a.y, 2);
    a.x += __shfl_xor(a.x, 4); a.y += __shfl_xor(a.y, 4);
    a.x += __shfl_xor(a.x, 8); a.y += __shfl_xor(a.y, 8);
    if (l == 0) {
        float2 self = q[i];
        float dv = dinv[i];
        nd[i] = make_float2(dv * (a.x + self.x) + C.x, dv * (a.y + self.y) + C.y);
    }
}

// ---------------- edge scoring: 8 B random reads from L2-resident nd ----------------
__global__ __launch_bounds__(256) void k_edge2(const int* __restrict__ src,
                                               const int* __restrict__ dst,
                                               const float2* __restrict__ nd,
                                               float* __restrict__ pred, int E) {
    int e = blockIdx.x * 256 + threadIdx.x;
    if (e >= E) return;
    pred[e] = nd[src[e]].x + nd[dst[e]].y;
}

extern "C" void kernel_launch(void* const* d_in, const int* in_sizes, int n_in,
                              void* d_out, int out_size, void* d_ws, size_t ws_size,
                              hipStream_t stream) {
    const float* x  = (const float*)d_in[0];
    const int*   ei = (const int*)d_in[1];
    const float* W1 = (const float*)d_in[2];
    const float* b1 = (const float*)d_in[3];
    const float* W2 = (const float*)d_in[4];
    const float* b2 = (const float*)d_in[5];
    const float* Wf = (const float*)d_in[6];
    const float* bf = (const float*)d_in[7];
    float* pred = (float*)d_out;

    const int N = N_NODES, E = N_EDGES;
    const int* src = ei;
    const int* dst = ei + E;

    // workspace (bytes); gt and q alias ebuf (dead after k_sort2h). Total ~33 MB.
    char* w = (char*)d_ws;
    int*      cursor = (int*)(w + 0x0);           // 25 KB (stride CPAD)
    float*    v2g    = (float*)(w + 0xC000);      // 128 B
    float*    dinv   = (float*)(w + 0x10000);     // 400 KB
    int2*     offseA = (int2*)(w + 0x80000);      // 800 KB
    int2*     offseB = (int2*)(w + 0x150000);     // 800 KB
    float2*   nd     = (float2*)(w + 0x220000);   // 800 KB
    unsigned* ebuf   = (unsigned*)(w + 0x3C0000); // 391*9216*4 = 14.42 MB (dead after sort2h)
    uint4*    gt     = (uint4*)(w + 0x3C0000);    // 3.2 MB (aliases ebuf; live gemm1->gather1)
    float2*   q      = (float2*)(w + 0x700000);   // 800 KB (aliases ebuf; live gather1->edge2)
    int*      ebuf2  = (int*)(w + 0x11A0000);     // 782*4608*4 = 14.42 MB -> end ~0x1FB0000

    const int B = 256;
    int gE   = (E + B - 1) / B;     // 12500
    int gN2  = (N + 127) / 128;     // 782 (gemm1, 2 lanes/row)
    int gN64 = (N * 64) / B;        // 25000 (wave per node)
    int gN16 = (N + 15) / 16;       // 6250 (16 lanes per node)

    hipMemsetAsync(cursor, 0, NB * CPAD * sizeof(int), stream);
    k_part<<<NCHUNK, 512, 0, stream>>>(src, dst, cursor, ebuf, E);
    k_sort2h<<<2 * NB, 512, 0, stream>>>(ebuf, cursor, ebuf2, offseA, offseB, N);
    k_gemm1<<<gN2, B, 0, stream>>>(x, W1, W2, Wf, offseA, offseB, dinv, gt, v2g, N);
    k_gather1<<<gN64, B, 0, stream>>>((const unsigned*)gt, offseA, offseB, ebuf2, dinv, b1,
                                      v2g, q, N);
    k_gather2<<<gN16, B, 0, stream>>>(q, offseA, offseB, ebuf2, dinv, b2, Wf, bf, nd, N);
    k_edge2<<<gE, B, 0, stream>>>(src, dst, nd, pred, E);
}

// Round 18
// 174.946 us; speedup vs baseline: 1.1505x; 1.0286x over previous
//
#include <hip/hip_runtime.h>
#include <hip/hip_fp16.h>

#define N_NODES 100000
#define N_EDGES 3200000
#define F_IN 128
#define HID 16

#define SHIFT 8
#define NPB 256                                 // nodes per bucket
#define NB 391                                  // ceil(N/256)
#define CHUNK 4096
#define NCHUNK ((N_EDGES + CHUNK - 1) / CHUNK)  // 782
#define MAXBE 9216                              // region cap per bucket (mean 8184, +11 sigma)
#define HALFR 4608                              // per half-sort output region
#define SMAX 9                                  // HALFR/512
#define CPAD 16

__device__ __forceinline__ float2 h2f(unsigned u) {
    __half2 h;
    *reinterpret_cast<unsigned*>(&h) = u;
    return __half22float2(h);
}
__device__ __forceinline__ unsigned f2h(float a, float b) {
    __half2 h = __floats2half2_rn(a, b);
    return *reinterpret_cast<unsigned*>(&h);
}

// ---------------- partition into 391 fixed bucket regions, 512 threads, wave-scan ----------------
__global__ __launch_bounds__(512) void k_part(const int* __restrict__ src,
                                              const int* __restrict__ dst,
                                              int* __restrict__ cursor,
                                              unsigned* __restrict__ ebuf, int E) {
    __shared__ int lcnt[512];
    __shared__ int lcur[512];
    __shared__ int dlt[512];
    __shared__ int wsum[8], wpre[8];
    __shared__ unsigned sbuf[CHUNK];         // 16 KB
    __shared__ unsigned short sbkt[CHUNK];   // 8 KB
    int t = threadIdx.x;
    int lane = t & 63, wid = t >> 6;
    lcnt[t] = 0;
    __syncthreads();
    int e0 = blockIdx.x * CHUNK;
    int ne = min(CHUNK, E - e0);
    for (int e = t; e < ne; e += 512) atomicAdd(&lcnt[dst[e0 + e] >> SHIFT], 1);
    __syncthreads();
    int v = lcnt[t];
    int s = v;
#pragma unroll
    for (int o = 1; o < 64; o <<= 1) {
        int u = __shfl_up(s, o);
        if (lane >= o) s += u;
    }
    if (lane == 63) wsum[wid] = s;
    __syncthreads();
    if (t == 0) {
        int r = 0;
#pragma unroll
        for (int k = 0; k < 8; k++) {
            wpre[k] = r;
            r += wsum[k];
        }
    }
    __syncthreads();
    int o = s + wpre[wid] - v;  // exclusive prefix
    lcur[t] = o;
    if (t < NB && v) dlt[t] = t * MAXBE + atomicAdd(&cursor[t * CPAD], v) - o;
    __syncthreads();
    for (int e = t; e < ne; e += 512) {
        int d = dst[e0 + e];
        int b = d >> SHIFT;
        int p = atomicAdd(&lcur[b], 1);
        sbuf[p] = ((unsigned)src[e0 + e] << SHIFT) | (unsigned)(d & (NPB - 1));
        sbkt[p] = (unsigned short)b;
    }
    __syncthreads();
    for (int k = t; k < ne; k += 512) ebuf[k + dlt[sbkt[k]]] = sbuf[k];
}

// ---------------- half-bucket sort by EDGE RANGE: block (b,h) sorts its half independently ----------------
__global__ __launch_bounds__(512) void k_sort2h(const unsigned* __restrict__ ebuf,
                                                const int* __restrict__ cursor,
                                                int* __restrict__ ebuf2,
                                                int2* __restrict__ offseA,
                                                int2* __restrict__ offseB, int N) {
    __shared__ int hist[NPB];
    __shared__ int cur[NPB];
    __shared__ int wsum[4], wpre[4];
    __shared__ int sbufS[HALFR];  // 18 KB
    int t = threadIdx.x;
    int lane = t & 63, wid = t >> 6;
    int b = blockIdx.x >> 1, h = blockIdx.x & 1;
    if (t < NPB) hist[t] = 0;
    __syncthreads();
    int cnt = min(cursor[b * CPAD], MAXBE);
    int mid = cnt >> 1;
    int lo = h ? mid : 0;
    int ne = (h ? cnt : mid) - lo;
    int base_r = b * MAXBE + lo;
    unsigned eu[SMAX];
    int nq = 0;
    for (int e = t; e < ne; e += 512) eu[nq++] = ebuf[base_r + e];
    for (int q = 0; q < nq; q++) atomicAdd(&hist[eu[q] & (NPB - 1u)], 1);
    __syncthreads();
    int base_w = blockIdx.x * HALFR;
    int v = (t < NPB) ? hist[t] : 0;
    if (t < NPB) {
        int s = v;
#pragma unroll
        for (int o = 1; o < 64; o <<= 1) {
            int u = __shfl_up(s, o);
            if (lane >= o) s += u;
        }
        if (lane == 63) wsum[wid] = s;
        hist[t] = s;  // stash wave-inclusive
    }
    __syncthreads();
    if (t == 0) {
        int r = 0;
#pragma unroll
        for (int k = 0; k < 4; k++) {
            wpre[k] = r;
            r += wsum[k];
        }
    }
    __syncthreads();
    if (t < NPB) {
        int ex = hist[t] + wpre[wid] - v;  // exclusive prefix
        cur[t] = ex;
        int i = b * NPB + t;
        if (i < N) {
            int2 oe = make_int2(base_w + ex, base_w + ex + v);
            if (h == 0) offseA[i] = oe;
            else        offseB[i] = oe;
        }
    }
    __syncthreads();
    for (int q = 0; q < nq; q++) {
        int p = atomicAdd(&cur[eu[q] & (NPB - 1u)], 1);
        sbufS[p] = (int)(eu[q] >> SHIFT);
    }
    __syncthreads();
    for (int k = t; k < ne; k += 512) ebuf2[base_w + k] = sbufS[k];  // coalesced
}

// ---------------- GEMM1: g = (x @ W1) * dinv, fp16 out; also v2g = W2@[wf_lo|wf_hi] (block 0) ----------------
__global__ __launch_bounds__(256) void k_gemm1(const float* __restrict__ x,
                                               const float* __restrict__ W1,
                                               const float* __restrict__ W2,
                                               const float* __restrict__ Wf,
                                               const int2* __restrict__ offseA,
                                               const int2* __restrict__ offseB,
                                               float* __restrict__ dinv,
                                               uint4* __restrict__ gt,
                                               float* __restrict__ v2g, int N) {
    __shared__ float w1s[F_IN * HID];  // 8 KB
    for (int idx = threadIdx.x; idx < F_IN * HID; idx += 256) w1s[idx] = W1[idx];
    if (blockIdx.x == 0 && threadIdx.x < 32) {
        int k = threadIdx.x & 15, hi = threadIdx.x >> 4;
        float s = 0.f;
#pragma unroll
        for (int n = 0; n < HID; n++) s += W2[k * HID + n] * Wf[hi * HID + n];
        v2g[threadIdx.x] = s;
    }
    __syncthreads();
    int t = threadIdx.x;
    int r = t >> 1, hf = t & 1;
    int i = blockIdx.x * 128 + r;
    float acc[HID];
#pragma unroll
    for (int n = 0; n < HID; n++) acc[n] = 0.f;
    if (i < N) {
        const float4* xr = (const float4*)(x + (size_t)i * F_IN + hf * (F_IN / 2));
#pragma unroll 4
        for (int k4 = 0; k4 < F_IN / 8; k4++) {
            float4 xv = xr[k4];
            int k = hf * (F_IN / 2) + k4 * 4;
#pragma unroll
            for (int n = 0; n < HID; n++) {
                acc[n] += xv.x * w1s[(k + 0) * HID + n] + xv.y * w1s[(k + 1) * HID + n] +
                          xv.z * w1s[(k + 2) * HID + n] + xv.w * w1s[(k + 3) * HID + n];
            }
        }
    }
#pragma unroll
    for (int n = 0; n < HID; n++) acc[n] += __shfl_xor(acc[n], 1);
    if (hf == 0 && i < N) {
        int2 oA = offseA[i], oB = offseB[i];
        int deg = (oA.y - oA.x) + (oB.y - oB.x);
        float dv = rsqrtf((float)(deg + 1));  // +1 self-loop
        dinv[i] = dv;
        uint4 w0, w1;
        w0.x = f2h(acc[0] * dv, acc[1] * dv);
        w0.y = f2h(acc[2] * dv, acc[3] * dv);
        w0.z = f2h(acc[4] * dv, acc[5] * dv);
        w0.w = f2h(acc[6] * dv, acc[7] * dv);
        w1.x = f2h(acc[8] * dv, acc[9] * dv);
        w1.y = f2h(acc[10] * dv, acc[11] * dv);
        w1.z = f2h(acc[12] * dv, acc[13] * dv);
        w1.w = f2h(acc[14] * dv, acc[15] * dv);
        gt[2 * (size_t)i] = w0;
        gt[2 * (size_t)i + 1] = w1;
    }
}

// ---------------- gather conv1, 16 edge slots x 4 uint2-slices + fused v2g dots ----------------
// Wave per node; lane = eo*4+s; each lane loads 8 B (4 fp16) per edge -> 16 edges in flight.
__global__ __launch_bounds__(256) void k_gather1(const uint2* __restrict__ gtu2,
                                                 const int2* __restrict__ offseA,
                                                 const int2* __restrict__ offseB,
                                                 const int* __restrict__ ebuf2,
                                                 const float* __restrict__ dinv,
                                                 const float* __restrict__ b1,
                                                 const float* __restrict__ v2g,
                                                 float2* __restrict__ q, int N) {
    int i = (blockIdx.x * 256 + threadIdx.x) >> 6;  // node = global wave id
    int lane = threadIdx.x & 63;
    if (i >= N) return;
    int eo = lane >> 2, s = lane & 3;
    int2 oA = offseA[i], oB = offseB[i];
    float4 a = make_float4(0.f, 0.f, 0.f, 0.f);
    for (int e = oA.x + eo; e < oA.y; e += 16) {
        uint2 u = gtu2[(size_t)ebuf2[e] * 4 + s];
        float2 f0 = h2f(u.x), f1 = h2f(u.y);
        a.x += f0.x; a.y += f0.y; a.z += f1.x; a.w += f1.y;
    }
    for (int e = oB.x + eo; e < oB.y; e += 16) {
        uint2 u = gtu2[(size_t)ebuf2[e] * 4 + s];
        float2 f0 = h2f(u.x), f1 = h2f(u.y);
        a.x += f0.x; a.y += f0.y; a.z += f1.x; a.w += f1.y;
    }
#pragma unroll
    for (int mk = 4; mk <= 32; mk <<= 1) {
        a.x += __shfl_xor(a.x, mk);
        a.y += __shfl_xor(a.y, mk);
        a.z += __shfl_xor(a.z, mk);
        a.w += __shfl_xor(a.w, mk);
    }
    if (eo == 0) {
        uint2 u = gtu2[(size_t)i * 4 + s];  // self-loop
        float2 f0 = h2f(u.x), f1 = h2f(u.y);
        a.x += f0.x; a.y += f0.y; a.z += f1.x; a.w += f1.y;
        float dv = dinv[i];
        float4 bb = ((const float4*)b1)[s];
        float o0 = fmaxf(dv * a.x + bb.x, 0.f);  // h1[4s]
        float o1 = fmaxf(dv * a.y + bb.y, 0.f);
        float o2 = fmaxf(dv * a.z + bb.z, 0.f);
        float o3 = fmaxf(dv * a.w + bb.w, 0.f);
        float4 vlo = ((const float4*)v2g)[s];
        float4 vhi = ((const float4*)v2g)[4 + s];
        float qs = o0 * vlo.x + o1 * vlo.y + o2 * vlo.z + o3 * vlo.w;
        float qd = o0 * vhi.x + o1 * vhi.y + o2 * vhi.z + o3 * vhi.w;
        qs += __shfl_xor(qs, 1); qd += __shfl_xor(qd, 1);
        qs += __shfl_xor(qs, 2); qd += __shfl_xor(qd, 2);
        if (s == 0) q[i] = make_float2(dv * qs, dv * qd);
    }
}

// ---------------- gather conv2 on scalars over two ranges ----------------
__global__ __launch_bounds__(256) void k_gather2(const float2* __restrict__ q,
                                                 const int2* __restrict__ offseA,
                                                 const int2* __restrict__ offseB,
                                                 const int* __restrict__ ebuf2,
                                                 const float* __restrict__ dinv,
                                                 const float* __restrict__ b2,
                                                 const float* __restrict__ Wf,
                                                 const float* __restrict__ bf,
                                                 float2* __restrict__ nd, int N) {
    __shared__ float2 C;
    if (threadIdx.x == 0) {
        float c1 = 0.f, c2 = 0.f;
#pragma unroll
        for (int k = 0; k < HID; k++) {
            c1 += b2[k] * Wf[k];
            c2 += b2[k] * Wf[16 + k];
        }
        C = make_float2(c1, c2 + bf[0]);
    }
    __syncthreads();
    int grp = threadIdx.x >> 4, l = threadIdx.x & 15;
    int i = blockIdx.x * 16 + grp;
    if (i >= N) return;
    int2 oA = offseA[i], oB = offseB[i];
    float2 a = make_float2(0.f, 0.f);
    for (int e = oA.x + l; e < oA.y; e += 16) {
        float2 qq = q[ebuf2[e]];
        a.x += qq.x;
        a.y += qq.y;
    }
    for (int e = oB.x + l; e < oB.y; e += 16) {
        float2 qq = q[ebuf2[e]];
        a.x += qq.x;
        a.y += qq.y;
    }
    a.x += __shfl_xor(a.x, 1); a.y += __shfl_xor(a.y, 1);
    a.x += __shfl_xor(a.x, 2); a.y += __shfl_xor(a.y, 2);
    a.x += __shfl_xor(a.x, 4); a.y += __shfl_xor(a.y, 4);
    a.x += __shfl_xor(a.x, 8); a.y += __shfl_xor(a.y, 8);
    if (l == 0) {
        float2 self = q[i];
        float dv = dinv[i];
        nd[i] = make_float2(dv * (a.x + self.x) + C.x, dv * (a.y + self.y) + C.y);
    }
}

// ---------------- edge scoring: 8 B random reads from L2-resident nd ----------------
__global__ __launch_bounds__(256) void k_edge2(const int* __restrict__ src,
                                               const int* __restrict__ dst,
                                               const float2* __restrict__ nd,
                                               float* __restrict__ pred, int E) {
    int e = blockIdx.x * 256 + threadIdx.x;
    if (e >= E) return;
    pred[e] = nd[src[e]].x + nd[dst[e]].y;
}

extern "C" void kernel_launch(void* const* d_in, const int* in_sizes, int n_in,
                              void* d_out, int out_size, void* d_ws, size_t ws_size,
                              hipStream_t stream) {
    const float* x  = (const float*)d_in[0];
    const int*   ei = (const int*)d_in[1];
    const float* W1 = (const float*)d_in[2];
    const float* b1 = (const float*)d_in[3];
    const float* W2 = (const float*)d_in[4];
    const float* b2 = (const float*)d_in[5];
    const float* Wf = (const float*)d_in[6];
    const float* bf = (const float*)d_in[7];
    float* pred = (float*)d_out;

    const int N = N_NODES, E = N_EDGES;
    const int* src = ei;
    const int* dst = ei + E;

    // workspace (bytes); gt and q alias ebuf (dead after k_sort2h). Total ~33 MB.
    char* w = (char*)d_ws;
    int*      cursor = (int*)(w + 0x0);           // 25 KB (stride CPAD)
    float*    v2g    = (float*)(w + 0xC000);      // 128 B
    float*    dinv   = (float*)(w + 0x10000);     // 400 KB
    int2*     offseA = (int2*)(w + 0x80000);      // 800 KB
    int2*     offseB = (int2*)(w + 0x150000);     // 800 KB
    float2*   nd     = (float2*)(w + 0x220000);   // 800 KB
    unsigned* ebuf   = (unsigned*)(w + 0x3C0000); // 391*9216*4 = 14.42 MB (dead after sort2h)
    uint4*    gt     = (uint4*)(w + 0x3C0000);    // 3.2 MB (aliases ebuf; live gemm1->gather1)
    float2*   q      = (float2*)(w + 0x700000);   // 800 KB (aliases ebuf; live gather1->edge2)
    int*      ebuf2  = (int*)(w + 0x11A0000);     // 782*4608*4 = 14.42 MB -> end ~0x1FB0000

    const int B = 256;
    int gE   = (E + B - 1) / B;     // 12500
    int gN2  = (N + 127) / 128;     // 782 (gemm1, 2 lanes/row)
    int gN64 = (N * 64) / B;        // 25000 (wave per node)
    int gN16 = (N + 15) / 16;       // 6250 (16 lanes per node)

    hipMemsetAsync(cursor, 0, NB * CPAD * sizeof(int), stream);
    k_part<<<NCHUNK, 512, 0, stream>>>(src, dst, cursor, ebuf, E);
    k_sort2h<<<2 * NB, 512, 0, stream>>>(ebuf, cursor, ebuf2, offseA, offseB, N);
    k_gemm1<<<gN2, B, 0, stream>>>(x, W1, W2, Wf, offseA, offseB, dinv, gt, v2g, N);
    k_gather1<<<gN64, B, 0, stream>>>((const uint2*)gt, offseA, offseB, ebuf2, dinv, b1,
                                      v2g, q, N);
    k_gather2<<<gN16, B, 0, stream>>>(q, offseA, offseB, ebuf2, dinv, b2, Wf, bf, nd, N);
    k_edge2<<<gE, B, 0, stream>>>(src, dst, nd, pred, E);
}

// Round 19
// 173.681 us; speedup vs baseline: 1.1589x; 1.0073x over previous
//
#include <hip/hip_runtime.h>
#include <hip/hip_fp16.h>

#define N_NODES 100000
#define N_EDGES 3200000
#define F_IN 128
#define HID 16

#define SHIFT 8
#define NPB 256                                 // nodes per bucket
#define NB 391                                  // ceil(N/256)
#define CHUNK 4096
#define NCHUNK ((N_EDGES + CHUNK - 1) / CHUNK)  // 782
#define MAXBE 9216                              // region cap per bucket (mean 8184, +11 sigma)
#define HALFR 4608                              // per half-sort output region
#define SMAX 9                                  // HALFR/512
#define CPAD 16

__device__ __forceinline__ float2 h2f(unsigned u) {
    __half2 h;
    *reinterpret_cast<unsigned*>(&h) = u;
    return __half22float2(h);
}
__device__ __forceinline__ unsigned f2h(float a, float b) {
    __half2 h = __floats2half2_rn(a, b);
    return *reinterpret_cast<unsigned*>(&h);
}

// ---------------- partition into 391 fixed bucket regions, 512 threads, wave-scan ----------------
__global__ __launch_bounds__(512) void k_part(const int* __restrict__ src,
                                              const int* __restrict__ dst,
                                              int* __restrict__ cursor,
                                              unsigned* __restrict__ ebuf, int E) {
    __shared__ int lcnt[512];
    __shared__ int lcur[512];
    __shared__ int dlt[512];
    __shared__ int wsum[8], wpre[8];
    __shared__ unsigned sbuf[CHUNK];         // 16 KB
    __shared__ unsigned short sbkt[CHUNK];   // 8 KB
    int t = threadIdx.x;
    int lane = t & 63, wid = t >> 6;
    lcnt[t] = 0;
    __syncthreads();
    int e0 = blockIdx.x * CHUNK;
    int ne = min(CHUNK, E - e0);
    for (int e = t; e < ne; e += 512) atomicAdd(&lcnt[dst[e0 + e] >> SHIFT], 1);
    __syncthreads();
    int v = lcnt[t];
    int s = v;
#pragma unroll
    for (int o = 1; o < 64; o <<= 1) {
        int u = __shfl_up(s, o);
        if (lane >= o) s += u;
    }
    if (lane == 63) wsum[wid] = s;
    __syncthreads();
    if (t == 0) {
        int r = 0;
#pragma unroll
        for (int k = 0; k < 8; k++) {
            wpre[k] = r;
            r += wsum[k];
        }
    }
    __syncthreads();
    int o = s + wpre[wid] - v;  // exclusive prefix
    lcur[t] = o;
    if (t < NB && v) dlt[t] = t * MAXBE + atomicAdd(&cursor[t * CPAD], v) - o;
    __syncthreads();
    for (int e = t; e < ne; e += 512) {
        int d = dst[e0 + e];
        int b = d >> SHIFT;
        int p = atomicAdd(&lcur[b], 1);
        sbuf[p] = ((unsigned)src[e0 + e] << SHIFT) | (unsigned)(d & (NPB - 1));
        sbkt[p] = (unsigned short)b;
    }
    __syncthreads();
    for (int k = t; k < ne; k += 512) ebuf[k + dlt[sbkt[k]]] = sbuf[k];
}

// ---------------- half-bucket sort by EDGE RANGE: block (b,h) sorts its half independently ----------------
__global__ __launch_bounds__(512) void k_sort2h(const unsigned* __restrict__ ebuf,
                                                const int* __restrict__ cursor,
                                                int* __restrict__ ebuf2,
                                                int2* __restrict__ offseA,
                                                int2* __restrict__ offseB, int N) {
    __shared__ int hist[NPB];
    __shared__ int cur[NPB];
    __shared__ int wsum[4], wpre[4];
    __shared__ int sbufS[HALFR];  // 18 KB
    int t = threadIdx.x;
    int lane = t & 63, wid = t >> 6;
    int b = blockIdx.x >> 1, h = blockIdx.x & 1;
    if (t < NPB) hist[t] = 0;
    __syncthreads();
    int cnt = min(cursor[b * CPAD], MAXBE);
    int mid = cnt >> 1;
    int lo = h ? mid : 0;
    int ne = (h ? cnt : mid) - lo;
    int base_r = b * MAXBE + lo;
    unsigned eu[SMAX];
    int nq = 0;
    for (int e = t; e < ne; e += 512) eu[nq++] = ebuf[base_r + e];
    for (int q = 0; q < nq; q++) atomicAdd(&hist[eu[q] & (NPB - 1u)], 1);
    __syncthreads();
    int base_w = blockIdx.x * HALFR;
    int v = (t < NPB) ? hist[t] : 0;
    if (t < NPB) {
        int s = v;
#pragma unroll
        for (int o = 1; o < 64; o <<= 1) {
            int u = __shfl_up(s, o);
            if (lane >= o) s += u;
        }
        if (lane == 63) wsum[wid] = s;
        hist[t] = s;  // stash wave-inclusive
    }
    __syncthreads();
    if (t == 0) {
        int r = 0;
#pragma unroll
        for (int k = 0; k < 4; k++) {
            wpre[k] = r;
            r += wsum[k];
        }
    }
    __syncthreads();
    if (t < NPB) {
        int ex = hist[t] + wpre[wid] - v;  // exclusive prefix
        cur[t] = ex;
        int i = b * NPB + t;
        if (i < N) {
            int2 oe = make_int2(base_w + ex, base_w + ex + v);
            if (h == 0) offseA[i] = oe;
            else        offseB[i] = oe;
        }
    }
    __syncthreads();
    for (int q = 0; q < nq; q++) {
        int p = atomicAdd(&cur[eu[q] & (NPB - 1u)], 1);
        sbufS[p] = (int)(eu[q] >> SHIFT);
    }
    __syncthreads();
    for (int k = t; k < ne; k += 512) ebuf2[base_w + k] = sbufS[k];  // coalesced
}

// ---------------- GEMM1: g = (x @ W1) * dinv, fp16 out; also v2g = W2@[wf_lo|wf_hi] (block 0) ----------------
__global__ __launch_bounds__(256) void k_gemm1(const float* __restrict__ x,
                                               const float* __restrict__ W1,
                                               const float* __restrict__ W2,
                                               const float* __restrict__ Wf,
                                               const int2* __restrict__ offseA,
                                               const int2* __restrict__ offseB,
                                               float* __restrict__ dinv,
                                               uint4* __restrict__ gt,
                                               float* __restrict__ v2g, int N) {
    __shared__ float w1s[F_IN * HID];  // 8 KB
    for (int idx = threadIdx.x; idx < F_IN * HID; idx += 256) w1s[idx] = W1[idx];
    if (blockIdx.x == 0 && threadIdx.x < 32) {
        int k = threadIdx.x & 15, hi = threadIdx.x >> 4;
        float s = 0.f;
#pragma unroll
        for (int n = 0; n < HID; n++) s += W2[k * HID + n] * Wf[hi * HID + n];
        v2g[threadIdx.x] = s;
    }
    __syncthreads();
    int t = threadIdx.x;
    int r = t >> 1, hf = t & 1;
    int i = blockIdx.x * 128 + r;
    float acc[HID];
#pragma unroll
    for (int n = 0; n < HID; n++) acc[n] = 0.f;
    if (i < N) {
        const float4* xr = (const float4*)(x + (size_t)i * F_IN + hf * (F_IN / 2));
#pragma unroll 4
        for (int k4 = 0; k4 < F_IN / 8; k4++) {
            float4 xv = xr[k4];
            int k = hf * (F_IN / 2) + k4 * 4;
#pragma unroll
            for (int n = 0; n < HID; n++) {
                acc[n] += xv.x * w1s[(k + 0) * HID + n] + xv.y * w1s[(k + 1) * HID + n] +
                          xv.z * w1s[(k + 2) * HID + n] + xv.w * w1s[(k + 3) * HID + n];
            }
        }
    }
#pragma unroll
    for (int n = 0; n < HID; n++) acc[n] += __shfl_xor(acc[n], 1);
    if (hf == 0 && i < N) {
        int2 oA = offseA[i], oB = offseB[i];
        int deg = (oA.y - oA.x) + (oB.y - oB.x);
        float dv = rsqrtf((float)(deg + 1));  // +1 self-loop
        dinv[i] = dv;
        uint4 w0, w1;
        w0.x = f2h(acc[0] * dv, acc[1] * dv);
        w0.y = f2h(acc[2] * dv, acc[3] * dv);
        w0.z = f2h(acc[4] * dv, acc[5] * dv);
        w0.w = f2h(acc[6] * dv, acc[7] * dv);
        w1.x = f2h(acc[8] * dv, acc[9] * dv);
        w1.y = f2h(acc[10] * dv, acc[11] * dv);
        w1.z = f2h(acc[12] * dv, acc[13] * dv);
        w1.w = f2h(acc[14] * dv, acc[15] * dv);
        gt[2 * (size_t)i] = w0;
        gt[2 * (size_t)i + 1] = w1;
    }
}

// ---------------- gather conv1, 32 edge slots x 2 uint4-slices + fused v2g dots ----------------
// Wave per node; lane = eo*2+s; each lane loads 16 B (8 fp16) per edge; 2-lane pair = full row.
__global__ __launch_bounds__(256) void k_gather1(const uint4* __restrict__ gtu4,
                                                 const int2* __restrict__ offseA,
                                                 const int2* __restrict__ offseB,
                                                 const int* __restrict__ ebuf2,
                                                 const float* __restrict__ dinv,
                                                 const float* __restrict__ b1,
                                                 const float* __restrict__ v2g,
                                                 float2* __restrict__ q, int N) {
    int i = (blockIdx.x * 256 + threadIdx.x) >> 6;  // node = global wave id
    int lane = threadIdx.x & 63;
    if (i >= N) return;
    int eo = lane >> 1, s = lane & 1;
    int2 oA = offseA[i], oB = offseB[i];
    float a0 = 0.f, a1 = 0.f, a2 = 0.f, a3 = 0.f, a4 = 0.f, a5 = 0.f, a6 = 0.f, a7 = 0.f;
    for (int e = oA.x + eo; e < oA.y; e += 32) {
        uint4 u = gtu4[(size_t)ebuf2[e] * 2 + s];
        float2 f0 = h2f(u.x), f1 = h2f(u.y), f2 = h2f(u.z), f3 = h2f(u.w);
        a0 += f0.x; a1 += f0.y; a2 += f1.x; a3 += f1.y;
        a4 += f2.x; a5 += f2.y; a6 += f3.x; a7 += f3.y;
    }
    for (int e = oB.x + eo; e < oB.y; e += 32) {
        uint4 u = gtu4[(size_t)ebuf2[e] * 2 + s];
        float2 f0 = h2f(u.x), f1 = h2f(u.y), f2 = h2f(u.z), f3 = h2f(u.w);
        a0 += f0.x; a1 += f0.y; a2 += f1.x; a3 += f1.y;
        a4 += f2.x; a5 += f2.y; a6 += f3.x; a7 += f3.y;
    }
#pragma unroll
    for (int mk = 2; mk <= 32; mk <<= 1) {
        a0 += __shfl_xor(a0, mk);
        a1 += __shfl_xor(a1, mk);
        a2 += __shfl_xor(a2, mk);
        a3 += __shfl_xor(a3, mk);
        a4 += __shfl_xor(a4, mk);
        a5 += __shfl_xor(a5, mk);
        a6 += __shfl_xor(a6, mk);
        a7 += __shfl_xor(a7, mk);
    }
    if (eo == 0) {  // lanes 0 (comps 0-7) and 1 (comps 8-15)
        uint4 u = gtu4[(size_t)i * 2 + s];  // self-loop
        float2 f0 = h2f(u.x), f1 = h2f(u.y), f2 = h2f(u.z), f3 = h2f(u.w);
        a0 += f0.x; a1 += f0.y; a2 += f1.x; a3 += f1.y;
        a4 += f2.x; a5 += f2.y; a6 += f3.x; a7 += f3.y;
        float dv = dinv[i];
        float4 bb0 = ((const float4*)b1)[2 * s];
        float4 bb1 = ((const float4*)b1)[2 * s + 1];
        float o0 = fmaxf(dv * a0 + bb0.x, 0.f);
        float o1 = fmaxf(dv * a1 + bb0.y, 0.f);
        float o2 = fmaxf(dv * a2 + bb0.z, 0.f);
        float o3 = fmaxf(dv * a3 + bb0.w, 0.f);
        float o4 = fmaxf(dv * a4 + bb1.x, 0.f);
        float o5 = fmaxf(dv * a5 + bb1.y, 0.f);
        float o6 = fmaxf(dv * a6 + bb1.z, 0.f);
        float o7 = fmaxf(dv * a7 + bb1.w, 0.f);
        float4 vl0 = ((const float4*)v2g)[2 * s];
        float4 vl1 = ((const float4*)v2g)[2 * s + 1];
        float4 vh0 = ((const float4*)v2g)[4 + 2 * s];
        float4 vh1 = ((const float4*)v2g)[4 + 2 * s + 1];
        float qs = o0 * vl0.x + o1 * vl0.y + o2 * vl0.z + o3 * vl0.w +
                   o4 * vl1.x + o5 * vl1.y + o6 * vl1.z + o7 * vl1.w;
        float qd = o0 * vh0.x + o1 * vh0.y + o2 * vh0.z + o3 * vh0.w +
                   o4 * vh1.x + o5 * vh1.y + o6 * vh1.z + o7 * vh1.w;
        qs += __shfl_xor(qs, 1);
        qd += __shfl_xor(qd, 1);
        if (s == 0) q[i] = make_float2(dv * qs, dv * qd);
    }
}

// ---------------- gather conv2 on scalars over two ranges ----------------
__global__ __launch_bounds__(256) void k_gather2(const float2* __restrict__ q,
                                                 const int2* __restrict__ offseA,
                                                 const int2* __restrict__ offseB,
                                                 const int* __restrict__ ebuf2,
                                                 const float* __restrict__ dinv,
                                                 const float* __restrict__ b2,
                                                 const float* __restrict__ Wf,
                                                 const float* __restrict__ bf,
                                                 float2* __restrict__ nd, int N) {
    __shared__ float2 C;
    if (threadIdx.x == 0) {
        float c1 = 0.f, c2 = 0.f;
#pragma unroll
        for (int k = 0; k < HID; k++) {
            c1 += b2[k] * Wf[k];
            c2 += b2[k] * Wf[16 + k];
        }
        C = make_float2(c1, c2 + bf[0]);
    }
    __syncthreads();
    int grp = threadIdx.x >> 4, l = threadIdx.x & 15;
    int i = blockIdx.x * 16 + grp;
    if (i >= N) return;
    int2 oA = offseA[i], oB = offseB[i];
    float2 a = make_float2(0.f, 0.f);
    for (int e = oA.x + l; e < oA.y; e += 16) {
        float2 qq = q[ebuf2[e]];
        a.x += qq.x;
        a.y += qq.y;
    }
    for (int e = oB.x + l; e < oB.y; e += 16) {
        float2 qq = q[ebuf2[e]];
        a.x += qq.x;
        a.y += qq.y;
    }
    a.x += __shfl_xor(a.x, 1); a.y += __shfl_xor(a.y, 1);
    a.x += __shfl_xor(a.x, 2); a.y += __shfl_xor(a.y, 2);
    a.x += __shfl_xor(a.x, 4); a.y += __shfl_xor(a.y, 4);
    a.x += __shfl_xor(a.x, 8); a.y += __shfl_xor(a.y, 8);
    if (l == 0) {
        float2 self = q[i];
        float dv = dinv[i];
        nd[i] = make_float2(dv * (a.x + self.x) + C.x, dv * (a.y + self.y) + C.y);
    }
}

// ---------------- edge scoring: 8 B random reads from L2-resident nd ----------------
__global__ __launch_bounds__(256) void k_edge2(const int* __restrict__ src,
                                               const int* __restrict__ dst,
                                               const float2* __restrict__ nd,
                                               float* __restrict__ pred, int E) {
    int e = blockIdx.x * 256 + threadIdx.x;
    if (e >= E) return;
    pred[e] = nd[src[e]].x + nd[dst[e]].y;
}

extern "C" void kernel_launch(void* const* d_in, const int* in_sizes, int n_in,
                              void* d_out, int out_size, void* d_ws, size_t ws_size,
                              hipStream_t stream) {
    const float* x  = (const float*)d_in[0];
    const int*   ei = (const int*)d_in[1];
    const float* W1 = (const float*)d_in[2];
    const float* b1 = (const float*)d_in[3];
    const float* W2 = (const float*)d_in[4];
    const float* b2 = (const float*)d_in[5];
    const float* Wf = (const float*)d_in[6];
    const float* bf = (const float*)d_in[7];
    float* pred = (float*)d_out;

    const int N = N_NODES, E = N_EDGES;
    const int* src = ei;
    const int* dst = ei + E;

    // workspace (bytes); gt and q alias ebuf (dead after k_sort2h). Total ~33 MB.
    char* w = (char*)d_ws;
    int*      cursor = (int*)(w + 0x0);           // 25 KB (stride CPAD)
    float*    v2g    = (float*)(w + 0xC000);      // 128 B
    float*    dinv   = (float*)(w + 0x10000);     // 400 KB
    int2*     offseA = (int2*)(w + 0x80000);      // 800 KB
    int2*     offseB = (int2*)(w + 0x150000);     // 800 KB
    float2*   nd     = (float2*)(w + 0x220000);   // 800 KB
    unsigned* ebuf   = (unsigned*)(w + 0x3C0000); // 391*9216*4 = 14.42 MB (dead after sort2h)
    uint4*    gt     = (uint4*)(w + 0x3C0000);    // 3.2 MB (aliases ebuf; live gemm1->gather1)
    float2*   q      = (float2*)(w + 0x700000);   // 800 KB (aliases ebuf; live gather1->edge2)
    int*      ebuf2  = (int*)(w + 0x11A0000);     // 782*4608*4 = 14.42 MB -> end ~0x1FB0000

    const int B = 256;
    int gE   = (E + B - 1) / B;     // 12500
    int gN2  = (N + 127) / 128;     // 782 (gemm1, 2 lanes/row)
    int gN64 = (N * 64) / B;        // 25000 (wave per node)
    int gN16 = (N + 15) / 16;       // 6250 (16 lanes per node)

    hipMemsetAsync(cursor, 0, NB * CPAD * sizeof(int), stream);
    k_part<<<NCHUNK, 512, 0, stream>>>(src, dst, cursor, ebuf, E);
    k_sort2h<<<2 * NB, 512, 0, stream>>>(ebuf, cursor, ebuf2, offseA, offseB, N);
    k_gemm1<<<gN2, B, 0, stream>>>(x, W1, W2, Wf, offseA, offseB, dinv, gt, v2g, N);
    k_gather1<<<gN64, B, 0, stream>>>((const uint4*)gt, offseA, offseB, ebuf2, dinv, b1,
                                      v2g, q, N);
    k_gather2<<<gN16, B, 0, stream>>>(q, offseA, offseB, ebuf2, dinv, b2, Wf, bf, nd, N);
    k_edge2<<<gE, B, 0, stream>>>(src, dst, nd, pred, E);
}